// Round 1
// baseline (18.362 us; speedup 1.0000x reference)
//
#include <hip/hip_runtime.h>

// Problem geometry:
//   x  : (1,64,28,28) f32   -> t3[c,h,w] = x[c,h,w] + x[c+32,h,w], c in [0,32)
//   roll +1 on width        -> t3r[c,h,w] = t3[c,h,(w+27)%28]
//   t5[h,w,k] = sum_{c<32, j<7} t3r[c,h,w+j-3] * w1[c,j,k]      (w zero-pad)
//   y[i,h,w]  = sum_{j2<3, k<21} t5[h+j2-1,w,k] * w0[i,j2,k]    (h zero-pad)
//   y : (1,256,28,28) f32

// ---------------- Kernel A: partial t5 over c-groups ----------------
// grid = 32 blocks: cg in [0,8) (4 channels each) x hg in [0,4) (7 rows each)
// block = 256 threads; 196 active compute lanes = (hh in [0,7)) x (w in [0,28))
// t5p layout: [cg][k][hw]  (cg*21+k)*784 + hw
__global__ __launch_bounds__(256) void convA(const float* __restrict__ x,
                                             const float* __restrict__ w1,
                                             float* __restrict__ t5p) {
    // LDS rows padded by 3 zeros each side: index w' stored at w'+3, row len 34
    __shared__ float t3s[4 * 7 * 34];
    const int tid = threadIdx.x;
    const int bx  = blockIdx.x;
    const int cg  = bx & 7;   // channel group, 4 channels
    const int hg  = bx >> 3;  // row group, 7 rows

    for (int idx = tid; idx < 4 * 7 * 34; idx += 256) t3s[idx] = 0.0f;
    __syncthreads();

    // stage t3r (sum + roll) for this block's 4 channels x 7 rows
    for (int idx = tid; idx < 4 * 196; idx += 256) {
        int cc = idx / 196;
        int r  = idx - cc * 196;
        int hh = r / 28;
        int w  = r - hh * 28;
        int c  = cg * 4 + cc;
        int h  = hg * 7 + hh;
        int wsrc = (w + 27) % 28;  // roll by +1
        float v = x[c * 784 + h * 28 + wsrc] + x[(c + 32) * 784 + h * 28 + wsrc];
        t3s[(cc * 7 + hh) * 34 + (w + 3)] = v;
    }
    __syncthreads();

    if (tid < 196) {
        int hh = tid / 28;
        int w  = tid - hh * 28;
        int hw = (hg * 7 + hh) * 28 + w;

        float acc[21];
#pragma unroll
        for (int k = 0; k < 21; ++k) acc[k] = 0.0f;

#pragma unroll
        for (int cc = 0; cc < 4; ++cc) {
#pragma unroll
            for (int j = 0; j < 7; ++j) {
                // t3r[c,h,w+j-3] with zero pad -> padded LDS index (w+j)
                float s = t3s[(cc * 7 + hh) * 34 + (w + j)];
                const float* wp = w1 + ((cg * 4 + cc) * 7 + j) * 21;  // wave-uniform
#pragma unroll
                for (int k = 0; k < 21; ++k) acc[k] = fmaf(s, wp[k], acc[k]);
            }
        }
#pragma unroll
        for (int k = 0; k < 21; ++k) t5p[(cg * 21 + k) * 784 + hw] = acc[k];
    }
}

// ---------------- Kernel A2: reduce 8 partials -> t5 [hw][24] ----------------
__global__ __launch_bounds__(256) void reduceA(const float* __restrict__ t5p,
                                               float* __restrict__ t5) {
    int t = blockIdx.x * 256 + threadIdx.x;
    if (t >= 24 * 784) return;
    int k  = t / 784;       // 0..23
    int hw = t - k * 784;   // 0..783
    float v = 0.0f;
    if (k < 21) {
#pragma unroll
        for (int g = 0; g < 8; ++g) v += t5p[(g * 21 + k) * 784 + hw];
    }
    t5[hw * 24 + k] = v;    // rows padded to 24 floats (96B, 16B-aligned)
}

// ---------------- Kernel B: final contraction with w0 ----------------
// grid = 256 blocks (one output channel i), block = 256 threads
__global__ __launch_bounds__(256) void convB(const float* __restrict__ t5,
                                             const float* __restrict__ w0,
                                             float* __restrict__ y) {
    const int i   = blockIdx.x;
    const float* wp = w0 + i * 63;  // wave-uniform -> scalar loads
    const int tid = threadIdx.x;

    for (int t = tid; t < 784; t += 256) {
        int h = t / 28;
        int w = t - h * 28;
        float acc = 0.0f;
#pragma unroll
        for (int j2 = 0; j2 < 3; ++j2) {
            int h2 = h + j2 - 1;
            if ((unsigned)h2 < 28u) {
                const float* tp = t5 + (h2 * 28 + w) * 24;
                const float* wq = wp + j2 * 21;
#pragma unroll
                for (int m = 0; m < 5; ++m) {
                    float4 v = *reinterpret_cast<const float4*>(tp + 4 * m);
                    acc = fmaf(v.x, wq[4 * m + 0], acc);
                    acc = fmaf(v.y, wq[4 * m + 1], acc);
                    acc = fmaf(v.z, wq[4 * m + 2], acc);
                    acc = fmaf(v.w, wq[4 * m + 3], acc);
                }
                acc = fmaf(tp[20], wq[20], acc);
            }
        }
        y[i * 784 + t] = acc;
    }
}

extern "C" void kernel_launch(void* const* d_in, const int* in_sizes, int n_in,
                              void* d_out, int out_size, void* d_ws, size_t ws_size,
                              hipStream_t stream) {
    const float* x  = (const float*)d_in[0];  // 64*28*28
    const float* w0 = (const float*)d_in[1];  // 256*3*21
    const float* w1 = (const float*)d_in[2];  // 32*7*21
    float* y   = (float*)d_out;               // 256*28*28
    float* t5p = (float*)d_ws;                // 8*21*784 floats
    float* t5  = t5p + 8 * 21 * 784;          // 784*24 floats

    hipLaunchKernelGGL(convA,   dim3(32),  dim3(256), 0, stream, x, w1, t5p);
    hipLaunchKernelGGL(reduceA, dim3(74),  dim3(256), 0, stream, t5p, t5);
    hipLaunchKernelGGL(convB,   dim3(256), dim3(256), 0, stream, t5, w0, y);
}

// Round 2
// 16.796 us; speedup vs baseline: 1.0932x; 1.0932x over previous
//
#include <hip/hip_runtime.h>

// One fused kernel, no grid sync. Block = (h0 in [0,28)) x (ig in [0,8)).
// Each block: recomputes t5 rows h0-1..h0+1 (c split 4-way in-block, LDS
// reduce), then produces y[ig*32..ig*32+32, h0, :].
//
//   t3r[c,h,w] = x[c,h,(w+27)%28] + x[c+32,h,(w+27)%28]
//   t5[h,w,k]  = sum_{c<32,j<7} t3r[c,h,w+j-3] * w1[c,j,k]   (w zero-pad)
//   y[i,h,w]   = sum_{j2<3,k<21} t5[h+j2-1,w,k] * w0[i,j2,k] (h zero-pad)

#define BLOCK 512

__global__ __launch_bounds__(BLOCK) void fused(const float* __restrict__ x,
                                               const float* __restrict__ w0,
                                               const float* __restrict__ w1,
                                               float* __restrict__ y) {
    __shared__ float t3s[3][32][34];                 // zero-margined rows (13 KB)
    __shared__ float part[4][84][21];                // c-quarter partials (28 KB)
    __shared__ __align__(16) float t5f[84][24];      // final t5 tile (8 KB)

    const int tid = threadIdx.x;
    const int h0  = blockIdx.x;   // output row
    const int ig  = blockIdx.y;   // output-channel group (32 ch)

    // ---- Phase A: stage t3r rows h0-1..h0+1 (zeros outside) ----
    for (int i = tid; i < 3 * 32 * 34; i += BLOCK) ((float*)t3s)[i] = 0.0f;
    __syncthreads();
    for (int idx = tid; idx < 3 * 32 * 28; idx += BLOCK) {
        int r   = idx / (32 * 28);
        int rem = idx - r * (32 * 28);
        int c   = rem / 28;
        int w   = rem - c * 28;
        int h   = h0 - 1 + r;
        if ((unsigned)h < 28u) {
            int wsrc = (w + 27) % 28;  // roll +1
            t3s[r][c][w + 3] =
                x[c * 784 + h * 28 + wsrc] + x[(c + 32) * 784 + h * 28 + wsrc];
        }
    }
    __syncthreads();

    // ---- Phase B: partial t5 over this thread's c-quarter ----
    // cq stride 128 -> wave-uniform; p in [0,84) = (r<3, w<28)
    const int cq = tid >> 7;
    const int p  = tid & 127;
    if (p < 84) {
        int r = p / 28;
        int w = p - r * 28;
        const float* w1b =
            w1 + (size_t)__builtin_amdgcn_readfirstlane(cq) * (8 * 7 * 21);

        float acc[21];
#pragma unroll
        for (int k = 0; k < 21; ++k) acc[k] = 0.0f;

        for (int cc = 0; cc < 8; ++cc) {
#pragma unroll
            for (int j = 0; j < 7; ++j) {
                float s = t3s[r][cq * 8 + cc][w + j];
                const float* wp = w1b + (cc * 7 + j) * 21;  // scalar (uniform)
#pragma unroll
                for (int k = 0; k < 21; ++k) acc[k] = fmaf(s, wp[k], acc[k]);
            }
        }
#pragma unroll
        for (int k = 0; k < 21; ++k) part[cq][p][k] = acc[k];
    }
    __syncthreads();

    // ---- Phase B2: reduce the 4 c-quarters into t5f[84][24] ----
    for (int o = tid; o < 84 * 21; o += BLOCK) {
        int pp = o / 21;
        int k  = o - pp * 21;
        t5f[pp][k] = part[0][pp][k] + part[1][pp][k] +
                     part[2][pp][k] + part[3][pp][k];
    }
    __syncthreads();

    // ---- Phase C: y[i, h0, w] for this block's 32 channels ----
    for (int o = tid; o < 32 * 28; o += BLOCK) {
        int ch = o / 28;
        int w  = o - ch * 28;
        int i  = ig * 32 + ch;
        const float* wrow = w0 + i * 63;
        float acc = 0.0f;
#pragma unroll
        for (int j2 = 0; j2 < 3; ++j2) {
            // t5f row j2*28+w IS t5[h0-1+j2, w, :] (zero if out of range)
            const float* tp = t5f[j2 * 28 + w];
            const float* wq = wrow + j2 * 21;
#pragma unroll
            for (int m = 0; m < 5; ++m) {
                float4 v = *reinterpret_cast<const float4*>(tp + 4 * m);
                acc = fmaf(v.x, wq[4 * m + 0], acc);
                acc = fmaf(v.y, wq[4 * m + 1], acc);
                acc = fmaf(v.z, wq[4 * m + 2], acc);
                acc = fmaf(v.w, wq[4 * m + 3], acc);
            }
            acc = fmaf(tp[20], wq[20], acc);
        }
        y[i * 784 + h0 * 28 + w] = acc;
    }
}

extern "C" void kernel_launch(void* const* d_in, const int* in_sizes, int n_in,
                              void* d_out, int out_size, void* d_ws, size_t ws_size,
                              hipStream_t stream) {
    const float* x  = (const float*)d_in[0];  // 64*28*28
    const float* w0 = (const float*)d_in[1];  // 256*3*21
    const float* w1 = (const float*)d_in[2];  // 32*7*21
    float* y = (float*)d_out;                 // 256*28*28

    hipLaunchKernelGGL(fused, dim3(28, 8), dim3(BLOCK), 0, stream, x, w0, w1, y);
}

// Round 3
// 13.472 us; speedup vs baseline: 1.3630x; 1.2468x over previous
//
#include <hip/hip_runtime.h>

// Fused, 1 launch. Block = (h0<28) x (ig<8), 512 threads.
//   t3r[c,h,w] = x[c,h,(w+27)%28] + x[c+32,h,(w+27)%28]
//   t5[h,w,k]  = sum_{c<32,j<7} t3r[c,h,w+j-3]*w1[c,j,k]   (w zero-pad)
//   y[i,h,w]   = sum_{j2<3,k<21} t5[h+j2-1,w,k]*w0[i,j2,k] (h zero-pad)
//
// Phase B done with MFMA 16x16x32 bf16 as 7 shifted-window GEMMs (K=c=32):
//   A_j[pos=(r,w)][c] = E[r][w+j][c]  (bf16, zero-margined)
//   B_j[c][kk]        = w1[c][j][kk]  (bf16, kk padded to 32)
// accumulated fp32 in AGPR/VGPR, unpacked to fp32 t5 tile in LDS.
// t3/w1 quantized to bf16; t5, w0 and final contraction stay fp32.

typedef __attribute__((ext_vector_type(8))) short short8;
typedef __attribute__((ext_vector_type(4))) float f32x4;

__device__ __forceinline__ unsigned short f2bf(float f) {
    union { float f; unsigned u; } v; v.f = f;
    unsigned r = v.u + 0x7FFFu + ((v.u >> 16) & 1u);  // RNE
    return (unsigned short)(r >> 16);
}

#define BLOCK 512

__global__ __launch_bounds__(BLOCK) void fused(const float* __restrict__ x,
                                               const float* __restrict__ w0,
                                               const float* __restrict__ w1,
                                               float* __restrict__ y) {
    // row strides 40 (ushort) / 36 (float): frag reads & t5 reads ~conflict-free
    __shared__ __align__(16) unsigned short Eb[4 * 34 * 40];  // [r][wext][c]
    __shared__ __align__(16) unsigned short Wb[7 * 32 * 40];  // [j][kk][c]
    __shared__ __align__(16) float t5f[96 * 36];              // [pos][k]

    const int tid = threadIdx.x;
    const int h0  = blockIdx.x;
    const int ig  = blockIdx.y;

    // ---- fill E: E[r][wext][c] = bf16(t3r[c, h0-1+r, wext-3]), zeros outside ----
    for (int idx = tid; idx < 4 * 34 * 32; idx += BLOCK) {
        int r    = idx / 1088;            // 1088 = 34*32
        int rem  = idx - r * 1088;
        int c    = rem / 34;
        int wext = rem - c * 34;          // inner -> coalesced x reads
        float val = 0.f;
        int h  = h0 - 1 + r;
        int wt = wext - 3;
        if (r < 3 && (unsigned)h < 28u && (unsigned)wt < 28u) {
            int wsrc = (wt + 27) % 28;    // roll +1
            val = x[c * 784 + h * 28 + wsrc] + x[(c + 32) * 784 + h * 28 + wsrc];
        }
        Eb[(r * 34 + wext) * 40 + c] = f2bf(val);
    }
    // ---- fill W: Wb[j][kk][c] = bf16(w1[c][j][kk]), kk in [21,32) -> 0 ----
    for (int idx = tid; idx < 7 * 32 * 32; idx += BLOCK) {
        int j   = idx / 1024;             // 1024 = 32*32
        int rem = idx - j * 1024;
        int c   = rem / 32;
        int kk  = rem - c * 32;           // inner -> coalesced w1 reads
        unsigned short val = 0;
        if (kk < 21) val = f2bf(w1[(c * 7 + j) * 21 + kk]);
        Wb[(j * 32 + kk) * 40 + c] = val;
    }
    __syncthreads();

    // ---- phase B: 6 waves, wave = M-tile (16 positions), both N-tiles ----
    const int wv = tid >> 6;
    const int l  = tid & 63;
    if (wv < 6) {
        int m   = l & 15;                 // M row within tile
        int pos = wv * 16 + m;            // pos = r*28+w (r==3 -> zero pad rows)
        int r   = pos / 28;
        int w   = pos - r * 28;
        int cb  = (l >> 4) << 3;          // k-chunk base (c), 8 contiguous
        const unsigned short* Ab = &Eb[(r * 34 + w) * 40 + cb];
        int kk0 = m, kk1 = m + 16;        // N cols
        const unsigned short* B0 = &Wb[kk0 * 40 + cb];
        const unsigned short* B1 = &Wb[kk1 * 40 + cb];
        f32x4 acc0 = {0.f, 0.f, 0.f, 0.f};
        f32x4 acc1 = {0.f, 0.f, 0.f, 0.f};
#pragma unroll
        for (int j = 0; j < 7; ++j) {
            short8 af = *(const short8*)(Ab + j * 40);     // A_j frag
            short8 b0 = *(const short8*)(B0 + j * 1280);   // 1280 = 32*40
            short8 b1 = *(const short8*)(B1 + j * 1280);
            acc0 = __builtin_amdgcn_mfma_f32_16x16x32_bf16(af, b0, acc0, 0, 0, 0);
            acc1 = __builtin_amdgcn_mfma_f32_16x16x32_bf16(af, b1, acc1, 0, 0, 0);
        }
        // D layout: col = lane&15, row = (lane>>4)*4 + q
        int rowb = wv * 16 + ((l >> 4) << 2);
#pragma unroll
        for (int q = 0; q < 4; ++q) {
            t5f[(rowb + q) * 36 + kk0] = acc0[q];
            t5f[(rowb + q) * 36 + kk1] = acc1[q];
        }
    }
    __syncthreads();

    // ---- phase C: y[i, h0, w] (unchanged from proven round-2 code) ----
    for (int o = tid; o < 32 * 28; o += BLOCK) {
        int ch = o / 28;
        int w  = o - ch * 28;
        int i  = ig * 32 + ch;
        const float* wrow = w0 + i * 63;
        float acc = 0.f;
#pragma unroll
        for (int j2 = 0; j2 < 3; ++j2) {
            const float* tp = &t5f[(j2 * 28 + w) * 36];  // t5[h0-1+j2, w, :]
            const float* wq = wrow + j2 * 21;
#pragma unroll
            for (int mq = 0; mq < 5; ++mq) {
                float4 v = *reinterpret_cast<const float4*>(tp + 4 * mq);
                acc = fmaf(v.x, wq[4 * mq + 0], acc);
                acc = fmaf(v.y, wq[4 * mq + 1], acc);
                acc = fmaf(v.z, wq[4 * mq + 2], acc);
                acc = fmaf(v.w, wq[4 * mq + 3], acc);
            }
            acc = fmaf(tp[20], wq[20], acc);
        }
        y[i * 784 + h0 * 28 + w] = acc;
    }
}

extern "C" void kernel_launch(void* const* d_in, const int* in_sizes, int n_in,
                              void* d_out, int out_size, void* d_ws, size_t ws_size,
                              hipStream_t stream) {
    const float* x  = (const float*)d_in[0];  // 64*28*28
    const float* w0 = (const float*)d_in[1];  // 256*3*21
    const float* w1 = (const float*)d_in[2];  // 32*7*21
    float* y = (float*)d_out;                 // 256*28*28

    hipLaunchKernelGGL(fused, dim3(28, 8), dim3(BLOCK), 0, stream, x, w0, w1, y);
}

// Round 4
// 10.661 us; speedup vs baseline: 1.7223x; 1.2636x over previous
//
#include <hip/hip_runtime.h>

// Fused, 1 launch, 2 barriers. Block = (h0<28) x (ig<8), 512 threads.
//   t3r[c,h,w] = x[c,h,(w+27)%28] + x[c+32,h,(w+27)%28]
//   t5[h,w,k]  = sum_{c<32,j<7} t3r[c,h,w+j-3]*w1[c,j,k]   (w zero-pad)
//   y[i,h,w]   = sum_{j2<3,k<21} t5[h+j2-1,w,k]*w0[i,j2,k] (h zero-pad)
// Phase B: MFMA 16x16x32 bf16, 7 shifted-window GEMMs (K=c=32).
// Staging: compile-time-trip unrolled batch loads (one latency exposure),
// predicated stores with select-0 covering all pad regions (no memset pass).

typedef __attribute__((ext_vector_type(8))) short short8;
typedef __attribute__((ext_vector_type(4))) float f32x4;

__device__ __forceinline__ unsigned short f2bf(float f) {
    union { float f; unsigned u; } v; v.f = f;
    unsigned r = v.u + 0x7FFFu + ((v.u >> 16) & 1u);  // RNE
    return (unsigned short)(r >> 16);
}

#define BLOCK 512

__global__ __launch_bounds__(BLOCK) void fused(const float* __restrict__ x,
                                               const float* __restrict__ w0,
                                               const float* __restrict__ w1,
                                               float* __restrict__ y) {
    __shared__ __align__(16) unsigned short Eb[4 * 34 * 40];  // [row=r*34+wext][c]
    __shared__ __align__(16) unsigned short Wb[7 * 32 * 40];  // [j*32+kk][c]
    __shared__ __align__(16) float t5f[96 * 36];              // [pos][k]
    __shared__ __align__(16) float w0s[32 * 72];              // [ch][j2*24+k]

    const int tid = threadIdx.x;
    const int h0  = blockIdx.x;
    const int ig  = blockIdx.y;

    // ---- Eb: full coverage of 136 rows x 32 c, batched loads ----
    // idx = r*1088 + c*34 + wext ; row = r*34+wext (== pad rows when invalid)
    {
        float v[9]; int dst[9]; bool ok[9];
#pragma unroll
        for (int q = 0; q < 9; ++q) {
            int idx  = tid + q * 512;
            bool in  = idx < 4352;
            int idx2 = in ? idx : 0;
            int r    = idx2 / 1088;
            int rem  = idx2 - r * 1088;
            int c    = rem / 34;
            int wext = rem - c * 34;
            int h    = h0 - 1 + r;
            int wt   = wext - 3;
            bool val = in && (r < 3) && ((unsigned)h < 28u) && ((unsigned)wt < 28u);
            int wsrc = (wt == 0) ? 27 : wt - 1;           // roll +1
            int a    = val ? (c * 784 + h * 28 + wsrc) : 0;
            float t  = x[a] + x[a + 25088];               // +32 channels
            v[q]   = val ? t : 0.f;
            dst[q] = (r * 34 + wext) * 40 + c;
            ok[q]  = in;
        }
#pragma unroll
        for (int q = 0; q < 9; ++q)
            if (ok[q]) Eb[dst[q]] = f2bf(v[q]);
    }

    // ---- Wb data: coalesced over w1 flat order f = c*147 + j*21 + kk ----
    {
        float v[10]; int dst[10]; bool ok[10];
#pragma unroll
        for (int q = 0; q < 10; ++q) {
            int f   = tid + q * 512;
            bool in = f < 4704;
            int f2  = in ? f : 0;
            int c   = f2 / 147;
            int rem = f2 - c * 147;
            int j   = rem / 21;
            int kk  = rem - j * 21;
            v[q]   = w1[f2];
            dst[q] = (j * 32 + kk) * 40 + c;
            ok[q]  = in;
        }
#pragma unroll
        for (int q = 0; q < 10; ++q)
            if (ok[q]) Wb[dst[q]] = f2bf(v[q]);
    }
    // Wb pad rows kk in [21,32): pure zero stores
    {
#pragma unroll
        for (int q = 0; q < 5; ++q) {
            int z = tid + q * 512;
            if (z < 2464) {
                int c  = z & 31;
                int t2 = z >> 5;          // 0..76
                int j  = t2 / 11;
                int kk = 21 + (t2 - j * 11);
                Wb[(j * 32 + kk) * 40 + c] = 0;
            }
        }
    }

    // ---- w0 slice for this ig -> LDS, padded [32][3][24] ----
    {
        float v[4]; int dst[4]; bool ok[4];
#pragma unroll
        for (int q = 0; q < 4; ++q) {
            int idx = tid + q * 512;
            bool in = idx < 2016;
            int i2  = in ? idx : 0;
            int ch  = i2 / 63;
            int rem = i2 - ch * 63;
            int j2  = rem / 21;
            int k   = rem - j2 * 21;
            v[q]   = w0[ig * 2016 + i2];
            dst[q] = ch * 72 + j2 * 24 + k;
            ok[q]  = in;
        }
#pragma unroll
        for (int q = 0; q < 4; ++q)
            if (ok[q]) w0s[dst[q]] = v[q];
    }
    __syncthreads();

    // ---- phase B: 6 waves, wave = M-tile (16 positions), both N-tiles ----
    const int wv = tid >> 6;
    const int l  = tid & 63;
    if (wv < 6) {
        int m   = l & 15;
        int pos = wv * 16 + m;            // r==3 -> zero-pad rows
        int r   = pos / 28;
        int w   = pos - r * 28;
        int cb  = (l >> 4) << 3;
        const unsigned short* Ab = &Eb[(r * 34 + w) * 40 + cb];
        int kk0 = m, kk1 = m + 16;
        const unsigned short* B0 = &Wb[kk0 * 40 + cb];
        const unsigned short* B1 = &Wb[kk1 * 40 + cb];
        f32x4 acc0 = {0.f, 0.f, 0.f, 0.f};
        f32x4 acc1 = {0.f, 0.f, 0.f, 0.f};
#pragma unroll
        for (int j = 0; j < 7; ++j) {
            short8 af = *(const short8*)(Ab + j * 40);
            short8 b0 = *(const short8*)(B0 + j * 1280);   // 1280 = 32*40
            short8 b1 = *(const short8*)(B1 + j * 1280);
            acc0 = __builtin_amdgcn_mfma_f32_16x16x32_bf16(af, b0, acc0, 0, 0, 0);
            acc1 = __builtin_amdgcn_mfma_f32_16x16x32_bf16(af, b1, acc1, 0, 0, 0);
        }
        int rowb = wv * 16 + ((l >> 4) << 2);   // D: col=lane&15, row=(l>>4)*4+q
#pragma unroll
        for (int q = 0; q < 4; ++q) {
            t5f[(rowb + q) * 36 + kk0] = acc0[q];
            t5f[(rowb + q) * 36 + kk1] = acc1[q];
        }
    }
    __syncthreads();

    // ---- phase C: y[i, h0, w], all-LDS operands ----
    for (int o = tid; o < 32 * 28; o += BLOCK) {
        int ch = o / 28;
        int w  = o - ch * 28;
        float acc = 0.f;
#pragma unroll
        for (int j2 = 0; j2 < 3; ++j2) {
            const float* tp = &t5f[(j2 * 28 + w) * 36];   // t5[h0-1+j2, w, :]
            const float* wq = &w0s[ch * 72 + j2 * 24];
#pragma unroll
            for (int mq = 0; mq < 5; ++mq) {
                float4 v = *reinterpret_cast<const float4*>(tp + 4 * mq);
                acc = fmaf(v.x, wq[4 * mq + 0], acc);
                acc = fmaf(v.y, wq[4 * mq + 1], acc);
                acc = fmaf(v.z, wq[4 * mq + 2], acc);
                acc = fmaf(v.w, wq[4 * mq + 3], acc);
            }
            acc = fmaf(tp[20], wq[20], acc);
        }
        y[(ig * 32 + ch) * 784 + h0 * 28 + w] = acc;
    }
}

extern "C" void kernel_launch(void* const* d_in, const int* in_sizes, int n_in,
                              void* d_out, int out_size, void* d_ws, size_t ws_size,
                              hipStream_t stream) {
    const float* x  = (const float*)d_in[0];  // 64*28*28
    const float* w0 = (const float*)d_in[1];  // 256*3*21
    const float* w1 = (const float*)d_in[2];  // 32*7*21
    float* y = (float*)d_out;                 // 256*28*28

    hipLaunchKernelGGL(fused, dim3(28, 8), dim3(BLOCK), 0, stream, x, w0, w1, y);
}

// Round 5
// 10.039 us; speedup vs baseline: 1.8291x; 1.0620x over previous
//
#include <hip/hip_runtime.h>
#include <hip/hip_bf16.h>

// Fused, 1 launch, 2 barriers. Block = (h0<28) x (ig<8), 512 threads.
//   t3r[c,h,w] = x[c,h,(w+27)%28] + x[c+32,h,(w+27)%28]
//   t5[h,w,k]  = sum_{c<32,j<7} t3r[c,h,w+j-3]*w1[c,j,k]   (w zero-pad)
//   y[i,h,w]   = sum_{j2<3,k<21} t5[h+j2-1,w,k]*w0[i,j2,k] (h zero-pad)
// Phase B: MFMA 16x16x32 bf16, 7 shifted-window GEMMs (K=c=32) -> bf16 Bb tile.
// Phase C: MFMA 16x16x32 bf16, y = w0b(32x64) x Bb(64x28), K = j2*21+kk (63+pad).
// Garbage-tolerant zones (never read / killed by zero operand): Eb r=3 rows,
// Wb kk>=21 rows, Bb k=63 col (w0b[.,63]=0), Bb rows w>=28, D rows/cols unused.

typedef __attribute__((ext_vector_type(8))) short short8;
typedef __attribute__((ext_vector_type(4))) float f32x4;

__device__ __forceinline__ unsigned short f2bf(float f) {
    union { __hip_bfloat16 h; unsigned short u; } cv;
    cv.h = __float2bfloat16(f);   // RNE hardware cvt
    return cv.u;
}

#define BLOCK 512

__global__ __launch_bounds__(BLOCK) void fused(const float* __restrict__ x,
                                               const float* __restrict__ w0,
                                               const float* __restrict__ w1,
                                               float* __restrict__ y) {
    __shared__ __align__(16) unsigned short Eb[4 * 34 * 40];  // [row=r*34+wext][c]
    __shared__ __align__(16) unsigned short Wb[7 * 32 * 40];  // [j*32+kk][c]
    __shared__ __align__(16) unsigned short Bb[32 * 72];      // [w][k=j2*21+kk]
    __shared__ __align__(16) unsigned short w0b[32 * 72];     // [ch][k], k63=0

    const int tid = threadIdx.x;
    const int h0  = blockIdx.x;
    const int ig  = blockIdx.y;

    // ---- Eb: float4 slots, slot s=(r<3, c<32, m<7); roll -> dst shift ----
    float4 e4[2]; int ebase[2]; int espec[2]; bool eok[2];
#pragma unroll
    for (int q = 0; q < 2; ++q) {
        int s   = tid + q * 512;
        bool in = (q == 0) || (s < 672);
        int s2  = in ? s : 0;
        int t   = s2 / 7;             // 0..95
        int m   = s2 - t * 7;         // float4 index within row
        int c   = t & 31;
        int r   = t >> 5;             // 0..2
        int h   = h0 - 1 + r;
        bool hv = (unsigned)h < 28u;
        int a   = hv ? (c * 784 + h * 28 + 4 * m) : 0;
        float4 va = *(const float4*)(x + a);
        float4 vb = *(const float4*)(x + a + 25088);
        float4 sv;
        sv.x = hv ? va.x + vb.x : 0.f;
        sv.y = hv ? va.y + vb.y : 0.f;
        sv.z = hv ? va.z + vb.z : 0.f;
        sv.w = hv ? va.w + vb.w : 0.f;
        e4[q] = sv;
        int dstb = (r * 34 + 4 * m + 4) * 40 + c;   // dst wext = src_w+4
        ebase[q] = dstb;
        espec[q] = (m == 6) ? ((r * 34 + 3) * 40 + c)   // src w=27 wraps to wext 3
                            : (dstb + 120);
        eok[q] = in;
    }

    // ---- Wb: flat w1 order, transpose-scatter; kk>=21 rows left garbage ----
    float vw1[10]; int wdst[10]; bool wok[10];
#pragma unroll
    for (int q = 0; q < 10; ++q) {
        int f   = tid + q * 512;
        bool in = f < 4704;
        int f2  = in ? f : 0;
        int c   = f2 / 147;
        int rem = f2 - c * 147;
        int j   = rem / 21;
        int kk  = rem - j * 21;
        vw1[q] = w1[f2];
        wdst[q] = (j * 32 + kk) * 40 + c;
        wok[q] = in;
    }

    // ---- w0b: bf16 [ch][72], k=63 zeroed ----
    float vw0[4]; int odst[4];
#pragma unroll
    for (int q = 0; q < 4; ++q) {
        int d  = tid + q * 512;       // < 2048 = 32ch x 64k
        int ch = d >> 6;
        int k  = d & 63;
        int ks = (k < 63) ? k : 0;
        float v = w0[ig * 2016 + ch * 63 + ks];
        vw0[q]  = (k < 63) ? v : 0.f;
        odst[q] = ch * 72 + k;
    }

    // ---- stores (loads above all in flight; one latency exposure) ----
#pragma unroll
    for (int q = 0; q < 2; ++q)
        if (eok[q]) {
            Eb[ebase[q]]      = f2bf(e4[q].x);
            Eb[ebase[q] + 40] = f2bf(e4[q].y);
            Eb[ebase[q] + 80] = f2bf(e4[q].z);
            Eb[espec[q]]      = f2bf(e4[q].w);
        }
    if (tid < 72) {   // margin rows wext {0,1,2,31,32,33} x r<3 : zeros
        int mr = tid >> 2, qq = tid & 3;
        int r  = mr / 6;
        int wi = mr - r * 6;
        int wext = wi + (wi >= 3 ? 28 : 0);
        float4 z = {0.f, 0.f, 0.f, 0.f};
        *(float4*)&Eb[(r * 34 + wext) * 40 + qq * 8] = z;
    }
#pragma unroll
    for (int q = 0; q < 10; ++q)
        if (wok[q]) Wb[wdst[q]] = f2bf(vw1[q]);
#pragma unroll
    for (int q = 0; q < 4; ++q) w0b[odst[q]] = f2bf(vw0[q]);
    __syncthreads();

    // ---- phase B: 6 waves, t5 tile -> bf16 Bb[w][j2*21+kk] ----
    const int wv = tid >> 6;
    const int l  = tid & 63;
    if (wv < 6) {
        int m   = l & 15;
        int pos = wv * 16 + m;        // pos >= 84 -> r=3 garbage (unused rows)
        int r   = pos / 28;
        int w   = pos - r * 28;
        int cb  = (l >> 4) << 3;
        const unsigned short* Ab = &Eb[(r * 34 + w) * 40 + cb];
        int kk0 = m, kk1 = m + 16;
        const unsigned short* B0 = &Wb[kk0 * 40 + cb];
        const unsigned short* B1 = &Wb[kk1 * 40 + cb];
        f32x4 acc0 = {0.f, 0.f, 0.f, 0.f};
        f32x4 acc1 = {0.f, 0.f, 0.f, 0.f};
#pragma unroll
        for (int j = 0; j < 7; ++j) {
            short8 af = *(const short8*)(Ab + j * 40);
            short8 b0 = *(const short8*)(B0 + j * 1280);   // 1280 = 32*40
            short8 b1 = *(const short8*)(B1 + j * 1280);
            acc0 = __builtin_amdgcn_mfma_f32_16x16x32_bf16(af, b0, acc0, 0, 0, 0);
            acc1 = __builtin_amdgcn_mfma_f32_16x16x32_bf16(af, b1, acc1, 0, 0, 0);
        }
        // D: col=lane&15, row=(l>>4)*4+q. rowb%4==0 & 28%4==0 -> same r for q=0..3
        int rowb = wv * 16 + ((l >> 4) << 2);
        int rr = rowb / 28;
        int ww = rowb - rr * 28;
        if (rr < 3) {                         // rows 84..95 unused (h pad)
            int base0 = ww * 72 + rr * 21 + kk0;
#pragma unroll
            for (int q2 = 0; q2 < 4; ++q2)
                Bb[base0 + q2 * 72] = f2bf(acc0[q2]);
            if (m < 5) {                      // kk1 < 21 only (else Wb garbage)
                int base1 = ww * 72 + rr * 21 + kk1;
#pragma unroll
                for (int q2 = 0; q2 < 4; ++q2)
                    Bb[base1 + q2 * 72] = f2bf(acc1[q2]);
            }
        }
    }
    __syncthreads();

    // ---- phase C: y(32x28) = w0b(32x64) x Bb^T, 4 waves x 2 MFMA ----
    if (wv < 4) {
        int mt = wv & 1, nt = wv >> 1;
        int col = l & 15, chunk = l >> 4;
        const unsigned short* Ap = &w0b[(mt * 16 + col) * 72 + chunk * 8];
        const unsigned short* Bp = &Bb[(nt * 16 + col) * 72 + chunk * 8];
        short8 a0 = *(const short8*)Ap;
        short8 b0 = *(const short8*)Bp;
        short8 a1 = *(const short8*)(Ap + 32);
        short8 b1 = *(const short8*)(Bp + 32);
        f32x4 acc = {0.f, 0.f, 0.f, 0.f};
        acc = __builtin_amdgcn_mfma_f32_16x16x32_bf16(a0, b0, acc, 0, 0, 0);
        acc = __builtin_amdgcn_mfma_f32_16x16x32_bf16(a1, b1, acc, 0, 0, 0);
        int wout = nt * 16 + col;
        if (wout < 28) {
            int chb = mt * 16 + (chunk << 2);   // D rows chb..chb+3
            float* yp = y + (ig * 32 + chb) * 784 + h0 * 28 + wout;
#pragma unroll
            for (int q2 = 0; q2 < 4; ++q2)
                yp[q2 * 784] = acc[q2];
        }
    }
}

extern "C" void kernel_launch(void* const* d_in, const int* in_sizes, int n_in,
                              void* d_out, int out_size, void* d_ws, size_t ws_size,
                              hipStream_t stream) {
    const float* x  = (const float*)d_in[0];  // 64*28*28
    const float* w0 = (const float*)d_in[1];  // 256*3*21
    const float* w1 = (const float*)d_in[2];  // 32*7*21
    float* y = (float*)d_out;                 // 256*28*28

    hipLaunchKernelGGL(fused, dim3(28, 8), dim3(BLOCK), 0, stream, x, w0, w1, y);
}

// Round 6
// 9.841 us; speedup vs baseline: 1.8658x; 1.0201x over previous
//
#include <hip/hip_runtime.h>
#include <hip/hip_bf16.h>

// Fused, 1 launch, 2 barriers. Block = (h0<28) x (ig<8), 512 threads.
//   t3r[c,h,w] = x[c,h,(w+27)%28] + x[c+32,h,(w+27)%28]
//   t5[h,w,k]  = sum_{c<32,j<7} t3r[c,h,w+j-3]*w1[c,j,k]   (w zero-pad)
//   y[i,h,w]   = sum_{j2<3,k<21} t5[h+j2-1,w,k]*w0[i,j2,k] (h zero-pad)
// Phase B: MFMA 16x16x32 bf16, 7 shifted-window GEMMs (K=c=32) -> bf16 Bb tile.
// Phase C: MFMA 16x16x32 bf16, y = w0b(32x64) x Bb(64x28), K = j2*21+kk (63+pad).
// Staging 3-way wave split (balanced ~130 VALU ops/thread):
//   all threads: Eb (2 float4-pair slots);  waves 0-5: Wb (3x float4, incr dst);
//   waves 6-7: w0b (4x float4, incr dst) + k63 zero col;  tid<72: Eb margins.
// Garbage-tolerant zones (never read / killed by zero operand): Eb r=3 rows,
// Wb kk>=21 rows, Bb k=63 col (w0b[.,63]=0), Bb rows w>=28, unused D rows/cols.

typedef __attribute__((ext_vector_type(8))) short short8;
typedef __attribute__((ext_vector_type(4))) float f32x4;

__device__ __forceinline__ unsigned short f2bf(float f) {
    union { __hip_bfloat16 h; unsigned short u; } cv;
    cv.h = __float2bfloat16(f);   // RNE hardware cvt
    return cv.u;
}

#define BLOCK 512

__global__ __launch_bounds__(BLOCK) void fused(const float* __restrict__ x,
                                               const float* __restrict__ w0,
                                               const float* __restrict__ w1,
                                               float* __restrict__ y) {
    __shared__ __align__(16) unsigned short Eb[4 * 34 * 40];  // [row=r*34+wext][c]
    __shared__ __align__(16) unsigned short Wb[7 * 32 * 40];  // [j*32+kk][c]
    __shared__ __align__(16) unsigned short Bb[32 * 72];      // [w][k=j2*21+kk]
    __shared__ __align__(16) unsigned short w0b[32 * 72];     // [ch][k], k63=0

    const int tid = threadIdx.x;
    const int h0  = blockIdx.x;
    const int ig  = blockIdx.y;
    const bool loW = tid < 384;   // waves 0-5

    // ---- Eb addr + loads (all threads): slot s=(r<3, c<32, m<7) ----
    float4 e4[2]; int ebase[2]; int espec[2]; bool eok[2];
#pragma unroll
    for (int q = 0; q < 2; ++q) {
        int s   = tid + q * 512;
        bool in = (q == 0) || (s < 672);
        int s2  = in ? s : 0;
        int t   = s2 / 7;             // 0..95
        int m   = s2 - t * 7;         // float4 index within row
        int c   = t & 31;
        int r   = t >> 5;             // 0..2
        int h   = h0 - 1 + r;
        bool hv = (unsigned)h < 28u;
        int a   = hv ? (c * 784 + h * 28 + 4 * m) : 0;
        float4 va = *(const float4*)(x + a);
        float4 vb = *(const float4*)(x + a + 25088);
        float4 sv;
        sv.x = hv ? va.x + vb.x : 0.f;
        sv.y = hv ? va.y + vb.y : 0.f;
        sv.z = hv ? va.z + vb.z : 0.f;
        sv.w = hv ? va.w + vb.w : 0.f;
        e4[q] = sv;
        int dstb = (r * 34 + 4 * m + 4) * 40 + c;       // dst wext = src_w+4
        ebase[q] = dstb;
        espec[q] = (m == 6) ? ((r * 34 + 3) * 40 + c)   // src w=27 wraps to wext 3
                            : (dstb + 120);
        eok[q] = in;
    }

    // ---- Wb addr + loads (waves 0-5): float4 over flat w1, incremental dst ----
    float4 wv4[4]; int wdst[4], wj[4], wkk[4]; bool wok[4];
    // ---- w0b addr + loads (waves 6-7): float4 over flat w0 slice ----
    float4 o4[4]; int odst[4], okk[4]; bool ook[4];
    if (loW) {
#pragma unroll
        for (int q = 0; q < 4; ++q) {
            int g   = tid + q * 384;
            bool in = g < 1176;           // q=3: tid<24
            int g2  = in ? g : 0;
            int f   = 4 * g2;             // flat = c*147 + j*21 + kk
            int c   = f / 147;
            int rem = f - c * 147;
            int j   = rem / 21;
            int kk  = rem - j * 21;
            wv4[q]  = *(const float4*)(w1 + f);
            wdst[q] = (j * 32 + kk) * 40 + c;
            wj[q] = j; wkk[q] = kk; wok[q] = in;
        }
    } else {
        int t2 = tid - 384;
#pragma unroll
        for (int q = 0; q < 4; ++q) {
            int g   = t2 + q * 128;
            bool in = g < 504;            // q=3: t2<120
            int g2  = in ? g : 0;
            int f   = 4 * g2;             // flat = ch*63 + k
            int ch  = f / 63;
            int k   = f - ch * 63;
            o4[q]   = *(const float4*)(w0 + ig * 2016 + f);
            odst[q] = ch * 72 + k;
            okk[q] = k; ook[q] = in;
        }
    }

    // ---- stores (all loads in flight; one latency exposure) ----
#pragma unroll
    for (int q = 0; q < 2; ++q)
        if (eok[q]) {
            Eb[ebase[q]]      = f2bf(e4[q].x);
            Eb[ebase[q] + 40] = f2bf(e4[q].y);
            Eb[ebase[q] + 80] = f2bf(e4[q].z);
            Eb[espec[q]]      = f2bf(e4[q].w);
        }
    if (tid < 72) {   // margin rows wext {0,1,2,31,32,33} x r<3 : zeros
        int mr = tid >> 2, qq = tid & 3;
        int r  = mr / 6;
        int wi = mr - r * 6;
        int wext = wi + (wi >= 3 ? 28 : 0);
        float4 z = {0.f, 0.f, 0.f, 0.f};
        *(float4*)&Eb[(r * 34 + wext) * 40 + qq * 8] = z;
    }
    if (loW) {
#pragma unroll
        for (int q = 0; q < 4; ++q)
            if (wok[q]) {
                int dst = wdst[q], j = wj[q], kk = wkk[q];
#define WADV() do { ++kk; dst += 40; \
                    if (kk == 21) { kk = 0; ++j; dst += 440; \
                        if (j == 7) { j = 0; dst -= 8959; } } } while (0)
                Wb[dst] = f2bf(wv4[q].x); WADV();
                Wb[dst] = f2bf(wv4[q].y); WADV();
                Wb[dst] = f2bf(wv4[q].z); WADV();
                Wb[dst] = f2bf(wv4[q].w);
#undef WADV
            }
    } else {
        int t2 = tid - 384;
#pragma unroll
        for (int q = 0; q < 4; ++q)
            if (ook[q]) {
                int dst = odst[q], k = okk[q];
#define OADV() do { ++k; ++dst; if (k == 63) { k = 0; dst += 9; } } while (0)
                w0b[dst] = f2bf(o4[q].x); OADV();
                w0b[dst] = f2bf(o4[q].y); OADV();
                w0b[dst] = f2bf(o4[q].z); OADV();
                w0b[dst] = f2bf(o4[q].w);
#undef OADV
            }
        if (t2 < 32) w0b[t2 * 72 + 63] = 0;   // K-pad column
    }
    __syncthreads();

    // ---- phase B: 6 waves, t5 tile -> bf16 Bb[w][j2*21+kk] ----
    const int wv = tid >> 6;
    const int l  = tid & 63;
    if (wv < 6) {
        int m   = l & 15;
        int pos = wv * 16 + m;        // pos >= 84 -> r=3 garbage (unused rows)
        int r   = pos / 28;
        int w   = pos - r * 28;
        int cb  = (l >> 4) << 3;
        const unsigned short* Ab = &Eb[(r * 34 + w) * 40 + cb];
        int kk0 = m, kk1 = m + 16;
        const unsigned short* B0 = &Wb[kk0 * 40 + cb];
        const unsigned short* B1 = &Wb[kk1 * 40 + cb];
        f32x4 acc0 = {0.f, 0.f, 0.f, 0.f};
        f32x4 acc1 = {0.f, 0.f, 0.f, 0.f};
#pragma unroll
        for (int j = 0; j < 7; ++j) {
            short8 af = *(const short8*)(Ab + j * 40);
            short8 b0 = *(const short8*)(B0 + j * 1280);   // 1280 = 32*40
            short8 b1 = *(const short8*)(B1 + j * 1280);
            acc0 = __builtin_amdgcn_mfma_f32_16x16x32_bf16(af, b0, acc0, 0, 0, 0);
            acc1 = __builtin_amdgcn_mfma_f32_16x16x32_bf16(af, b1, acc1, 0, 0, 0);
        }
        // D: col=lane&15, row=(l>>4)*4+q. rowb%4==0 & 28%4==0 -> same r for q=0..3
        int rowb = wv * 16 + ((l >> 4) << 2);
        int rr = rowb / 28;
        int ww = rowb - rr * 28;
        if (rr < 3) {                         // rows 84..95 unused (h pad)
            int base0 = ww * 72 + rr * 21 + kk0;
#pragma unroll
            for (int q2 = 0; q2 < 4; ++q2)
                Bb[base0 + q2 * 72] = f2bf(acc0[q2]);
            if (m < 5) {                      // kk1 < 21 only (else Wb garbage)
                int base1 = ww * 72 + rr * 21 + kk1;
#pragma unroll
                for (int q2 = 0; q2 < 4; ++q2)
                    Bb[base1 + q2 * 72] = f2bf(acc1[q2]);
            }
        }
    }
    __syncthreads();

    // ---- phase C: y(32x28) = w0b(32x64) x Bb^T, 4 waves x 2 MFMA ----
    if (wv < 4) {
        int mt = wv & 1, nt = wv >> 1;
        int col = l & 15, chunk = l >> 4;
        const unsigned short* Ap = &w0b[(mt * 16 + col) * 72 + chunk * 8];
        const unsigned short* Bp = &Bb[(nt * 16 + col) * 72 + chunk * 8];
        short8 a0 = *(const short8*)Ap;
        short8 b0 = *(const short8*)Bp;
        short8 a1 = *(const short8*)(Ap + 32);
        short8 b1 = *(const short8*)(Bp + 32);
        f32x4 acc = {0.f, 0.f, 0.f, 0.f};
        acc = __builtin_amdgcn_mfma_f32_16x16x32_bf16(a0, b0, acc, 0, 0, 0);
        acc = __builtin_amdgcn_mfma_f32_16x16x32_bf16(a1, b1, acc, 0, 0, 0);
        int wout = nt * 16 + col;
        if (wout < 28) {
            int chb = mt * 16 + (chunk << 2);   // D rows chb..chb+3
            float* yp = y + (ig * 32 + chb) * 784 + h0 * 28 + wout;
#pragma unroll
            for (int q2 = 0; q2 < 4; ++q2)
                yp[q2 * 784] = acc[q2];
        }
    }
}

extern "C" void kernel_launch(void* const* d_in, const int* in_sizes, int n_in,
                              void* d_out, int out_size, void* d_ws, size_t ws_size,
                              hipStream_t stream) {
    const float* x  = (const float*)d_in[0];  // 64*28*28
    const float* w0 = (const float*)d_in[1];  // 256*3*21
    const float* w1 = (const float*)d_in[2];  // 32*7*21
    float* y = (float*)d_out;                 // 256*28*28

    hipLaunchKernelGGL(fused, dim3(28, 8), dim3(BLOCK), 0, stream, x, w0, w1, y);
}